// Round 7
// baseline (72.872 us; speedup 1.0000x reference)
//
#include <hip/hip_runtime.h>
#include <stdint.h>

// MajFC: out[b,c] = 2.25 * sum_g clip(sum_{k<3} sign(x[b,3g+k])*sign(w[c,3g+k]), -1, 1)
// Sign-only bitplanes (absmax 0.0 verified R3-R6): t = px ^ pw,
// clip(group) = 1 - 2*maj(t0,t1,t2), out = 2.25*(1024 - 2*popc_total).
//
// Permutation trick: popc-sum is invariant under any (group,slot)->(bit,plane)
// bijection applied identically to x and w: element e = 768q + 12l + 3j + k ->
// plane [q][3j+k] bit l. Each lane packs 3 contiguous float4s (coalesced).
//
// Structure (R7): two dispatches (cross-block fences cost ~60us here - R3/R5).
//   1) pack_signs: 1280 blocks, ONE chunk-job per wave (max MLP; R4 had 5
//      serial jobs/wave = 5 chained HBM latencies on the critical path).
//   2) maj_main: BT=4 b-rows/thread, 256 blocks. Halves wpk re-read traffic
//      (50->25 MB) and amortizes W loads over 4 acc chains. cq = blk&3 keeps
//      c-quarter <-> XCD affinity under round-robin dispatch (wpk quarter
//      L2-resident). x planes via wave-uniform scalar loads (beat R6's
//      in-block pack).

#define C_IN  3072
#define C_OUT 1024
#define CHUNKS_W 4096          // 1024 w-rows * 4 chunks
#define CHUNKS_TOT 5120        // + 256 x-rows * 4 chunks

// ws layout:
//   wpk: [q][c][12]  uint64 -> 393216 B  (96 B contiguous per (q,c))
//   xpk: [b][q][12]  uint64 ->  98304 B  (wave-uniform scalar reads)

__global__ __launch_bounds__(256) void pack_signs(const float* __restrict__ x,
                                                  const float* __restrict__ w,
                                                  uint64_t* __restrict__ wpk,
                                                  uint64_t* __restrict__ xpk) {
    int j    = blockIdx.x * 4 + (threadIdx.x >> 6);   // chunk-job 0..5119
    int lane = threadIdx.x & 63;
    const float* src;
    uint64_t* dst;
    if (j < CHUNKS_W) {
        int c = j >> 2, q = j & 3;
        src = w + (size_t)c * C_IN + q * 768;
        dst = wpk + ((size_t)q * C_OUT + c) * 12;
    } else {
        int id = j - CHUNKS_W;
        int b = id >> 2, q = id & 3;
        src = x + (size_t)b * C_IN + q * 768;
        dst = xpk + ((size_t)b * 4 + q) * 12;
    }
    const float4* s4 = (const float4*)(src + 12 * lane);
    float4 f0 = s4[0], f1 = s4[1], f2 = s4[2];
    float v[12] = {f0.x, f0.y, f0.z, f0.w,
                   f1.x, f1.y, f1.z, f1.w,
                   f2.x, f2.y, f2.z, f2.w};
    uint64_t pl[12];
#pragma unroll
    for (int m = 0; m < 12; ++m)
        pl[m] = __ballot(v[m] > 0.0f);
    if (lane == 0) {
#pragma unroll
        for (int m = 0; m < 12; ++m)
            dst[m] = pl[m];   // ballots are wave-uniform; 96 B contiguous
    }
}

// ---- main: 4 b-rows per thread, one c per thread ---------------------------
__global__ __launch_bounds__(256) void maj_main(const uint64_t* __restrict__ wpk,
                                                const uint64_t* __restrict__ xpk,
                                                float* __restrict__ out) {
    int tid = threadIdx.x;
    int blk = blockIdx.x;               // 256 blocks
    int cq  = blk & 3;                  // c-quarter (XCD-affine under %8 rr)
    int b0  = (blk >> 2) * 4;           // 4 b-rows
    int c   = cq * 256 + tid;

    int acc[4] = {0, 0, 0, 0};
#pragma unroll
    for (int q = 0; q < 4; ++q) {
        const uint64_t* wb = wpk + ((size_t)q * C_OUT + c) * 12;  // 96 B contiguous
        uint64_t Wv[12];
#pragma unroll
        for (int m = 0; m < 12; ++m) Wv[m] = wb[m];
#pragma unroll
        for (int bi = 0; bi < 4; ++bi) {
            // wave-uniform address -> scalar loads on the SMEM pipe
            const uint64_t* xr = xpk + ((size_t)(b0 + bi) * 4 + q) * 12;
#pragma unroll
            for (int j = 0; j < 4; ++j) {
                uint64_t t0 = xr[3 * j + 0] ^ Wv[3 * j + 0];
                uint64_t t1 = xr[3 * j + 1] ^ Wv[3 * j + 1];
                uint64_t t2 = xr[3 * j + 2] ^ Wv[3 * j + 2];
                acc[bi] += __popcll((t0 & t1) | (t2 & (t0 | t1)));
            }
        }
    }
#pragma unroll
    for (int bi = 0; bi < 4; ++bi)
        out[(size_t)(b0 + bi) * C_OUT + c] = 2304.0f - 4.5f * (float)acc[bi];
}

extern "C" void kernel_launch(void* const* d_in, const int* in_sizes, int n_in,
                              void* d_out, int out_size, void* d_ws, size_t ws_size,
                              hipStream_t stream) {
    const float* x = (const float*)d_in[0];   // [256, 3072] f32
    const float* w = (const float*)d_in[1];   // [1024, 3072] f32
    float* out = (float*)d_out;               // [256, 1024] f32

    uint64_t* wpk = (uint64_t*)d_ws;                         // 393216 B
    uint64_t* xpk = (uint64_t*)((char*)d_ws + 393216);       //  98304 B

    pack_signs<<<1280, 256, 0, stream>>>(x, w, wpk, xpk);
    maj_main<<<256, 256, 0, stream>>>(wpk, xpk, out);
}

// Round 8
// 70.536 us; speedup vs baseline: 1.0331x; 1.0331x over previous
//
#include <hip/hip_runtime.h>
#include <stdint.h>

// MajFC: out[b,c] = 2.25 * sum_g clip(sum_{k<3} sign(x[b,3g+k])*sign(w[c,3g+k]), -1, 1)
// Sign-only bitplanes (absmax 0.0 verified R3-R7): t = px ^ pw,
// clip(group) = 1 - 2*maj(t0,t1,t2), out = 2.25*(1024 - 2*popc_total).
//
// Permutation trick: popc-sum is invariant under any (group,slot)->(bit,plane)
// bijection applied identically to x and w: element e = 768q + 12l + 3j + k ->
// plane [q][3j+k] bit l. Each lane packs 3 contiguous float4s (coalesced 16B/lane).
//
// Structure (R8 = best-of): two dispatches (cross-block release/acquire fences
// measured ~60us here - R3/R5; do NOT fuse).
//   1) pack_signs: 1280 blocks, ONE chunk-job per wave (R7 pack: critical path
//      = 1 HBM latency + BW, vs R4's 5 chained latencies).
//   2) maj_main: BT=2, 512 blocks (R4 maj: best measured; 2 blocks/CU, short
//      dependent chains). W-planes as 96B-contiguous vector loads from L2,
//      x-planes as wave-uniform scalar (SMEM-pipe) loads.

#define C_IN  3072
#define C_OUT 1024
#define CHUNKS_W 4096          // 1024 w-rows * 4 chunks
#define CHUNKS_TOT 5120        // + 256 x-rows * 4 chunks

// ws layout:
//   wpk: [q][c][12]  uint64 -> 393216 B  (96 B contiguous per (q,c))
//   xpk: [b][q][12]  uint64 ->  98304 B  (wave-uniform scalar reads)

__global__ __launch_bounds__(256) void pack_signs(const float* __restrict__ x,
                                                  const float* __restrict__ w,
                                                  uint64_t* __restrict__ wpk,
                                                  uint64_t* __restrict__ xpk) {
    int j    = blockIdx.x * 4 + (threadIdx.x >> 6);   // chunk-job 0..5119
    int lane = threadIdx.x & 63;
    const float* src;
    uint64_t* dst;
    if (j < CHUNKS_W) {
        int c = j >> 2, q = j & 3;
        src = w + (size_t)c * C_IN + q * 768;
        dst = wpk + ((size_t)q * C_OUT + c) * 12;
    } else {
        int id = j - CHUNKS_W;
        int b = id >> 2, q = id & 3;
        src = x + (size_t)b * C_IN + q * 768;
        dst = xpk + ((size_t)b * 4 + q) * 12;
    }
    const float4* s4 = (const float4*)(src + 12 * lane);
    float4 f0 = s4[0], f1 = s4[1], f2 = s4[2];
    float v[12] = {f0.x, f0.y, f0.z, f0.w,
                   f1.x, f1.y, f1.z, f1.w,
                   f2.x, f2.y, f2.z, f2.w};
    uint64_t pl[12];
#pragma unroll
    for (int m = 0; m < 12; ++m)
        pl[m] = __ballot(v[m] > 0.0f);
    if (lane == 0) {
#pragma unroll
        for (int m = 0; m < 12; ++m)
            dst[m] = pl[m];   // ballots are wave-uniform; 96 B contiguous
    }
}

// ---- main: 2 b-rows per thread, one c per thread (R4-proven) ---------------
__global__ __launch_bounds__(256) void maj_main(const uint64_t* __restrict__ wpk,
                                                const uint64_t* __restrict__ xpk,
                                                float* __restrict__ out) {
    int tid = threadIdx.x;
    int blk = blockIdx.x;               // 512 blocks
    int b0  = (blk >> 2) * 2;
    int c   = (blk & 3) * 256 + tid;

    int acc0 = 0, acc1 = 0;
#pragma unroll
    for (int q = 0; q < 4; ++q) {
        const uint64_t* wb = wpk + ((size_t)q * C_OUT + c) * 12;    // 96 B contiguous
        const uint64_t* x0 = xpk + ((size_t)(b0 + 0) * 4 + q) * 12; // wave-uniform
        const uint64_t* x1 = xpk + ((size_t)(b0 + 1) * 4 + q) * 12;
        uint64_t Wv[12];
#pragma unroll
        for (int m = 0; m < 12; ++m) Wv[m] = wb[m];
#pragma unroll
        for (int j = 0; j < 4; ++j) {
            uint64_t t0 = x0[3 * j + 0] ^ Wv[3 * j + 0];
            uint64_t t1 = x0[3 * j + 1] ^ Wv[3 * j + 1];
            uint64_t t2 = x0[3 * j + 2] ^ Wv[3 * j + 2];
            acc0 += __popcll((t0 & t1) | (t2 & (t0 | t1)));
            uint64_t u0 = x1[3 * j + 0] ^ Wv[3 * j + 0];
            uint64_t u1 = x1[3 * j + 1] ^ Wv[3 * j + 1];
            uint64_t u2 = x1[3 * j + 2] ^ Wv[3 * j + 2];
            acc1 += __popcll((u0 & u1) | (u2 & (u0 | u1)));
        }
    }
    out[(size_t)(b0 + 0) * C_OUT + c] = 2304.0f - 4.5f * (float)acc0;
    out[(size_t)(b0 + 1) * C_OUT + c] = 2304.0f - 4.5f * (float)acc1;
}

extern "C" void kernel_launch(void* const* d_in, const int* in_sizes, int n_in,
                              void* d_out, int out_size, void* d_ws, size_t ws_size,
                              hipStream_t stream) {
    const float* x = (const float*)d_in[0];   // [256, 3072] f32
    const float* w = (const float*)d_in[1];   // [1024, 3072] f32
    float* out = (float*)d_out;               // [256, 1024] f32

    uint64_t* wpk = (uint64_t*)d_ws;                         // 393216 B
    uint64_t* xpk = (uint64_t*)((char*)d_ws + 393216);       //  98304 B

    pack_signs<<<1280, 256, 0, stream>>>(x, w, wpk, xpk);
    maj_main<<<512, 256, 0, stream>>>(wpk, xpk, out);
}